// Round 4
// baseline (964.484 us; speedup 1.0000x reference)
//
#include <hip/hip_runtime.h>
#include <stdint.h>
#include <math.h>

#define N_NODES  10000
#define N_EDGES  5000000
#define BATCH    2000
#define N_PAIRS  1999000   // BATCH*(BATCH-1)/2

// Output offsets (float32 elements), concatenated in reference return order
#define OUT_BN      0
#define OUT_PAIRS0  2000
#define OUT_PAIRS1  2001000
#define OUT_ES0     4000000
#define OUT_ES1     9000000
#define OUT_T       14000000
#define OUT_S       19000000
#define OUT_M       24000000

// Workspace layout (bytes)
#define WS_KEYS     0          // 10000 x u64
#define WS_SEL      80000      // 10000 x i32
#define WS_BN       120000     // 2000  x i32
#define WS_CNT      128000     // 10000 x i32   (zeroed by memset)
#define WS_FILL     168000     // 10000 x i32   (init to off[] by k_scan_all)
#define WS_OFF      208000     // 10001 x i32
#define WS_SCRATCH  248008     // 5M x u32 edge indices (compact layout)

// ---------------------------------------------------------------------------
// Gumbel score -> descending-sortable key with ascending-index tiebreak.
__device__ __forceinline__ unsigned long long score_key(int w, unsigned bits) {
  const float TINY = 1.17549435e-38f;
  float uf = __uint_as_float((bits >> 9) | 0x3f800000u) - 1.0f;
  float val = fmaxf(TINY, uf + TINY);
  float t1 = (float)log((double)val);            // inner log, rounded to f32
  float gmb = -(float)log((double)(-t1));        // outer log on f32-rounded input
  float score = (w > 0) ? ((float)log((double)w) + gmb) : (-INFINITY);
  unsigned fb = __float_as_uint(score);
  unsigned s = (fb & 0x80000000u) ? ~fb : (fb | 0x80000000u);
  unsigned d = ~s;
  return ((unsigned long long)d << 32) | (unsigned)w;
}

// JAX threefry2x32, partitionable mode: (x0,x1)=(0,i)+key; bits = out0^out1.
__global__ void k_scores(unsigned long long* __restrict__ keys) {
  int v = blockIdx.x * blockDim.x + threadIdx.x;
  if (v >= N_NODES) return;
  unsigned ks[3] = {0u, 19u, 0u ^ 19u ^ 0x1BD11BDAu};
  unsigned x0 = 0u + ks[0];
  unsigned x1 = (unsigned)v + ks[1];
  const int R0[4] = {13, 15, 26, 6};
  const int R1[4] = {17, 29, 16, 24};
#pragma unroll
  for (int g = 0; g < 5; ++g) {
    const int* R = (g & 1) ? R1 : R0;
#pragma unroll
    for (int r = 0; r < 4; ++r) {
      x0 += x1;
      x1 = (x1 << R[r]) | (x1 >> (32 - R[r]));
      x1 ^= x0;
    }
    x0 += ks[(g + 1) % 3];
    x1 += ks[(g + 2) % 3] + (unsigned)(g + 1);
  }
  keys[v] = score_key(v, x0 ^ x1);
}

// Rank each node's key among all 10000 (unique keys); selected iff rank < 2000.
__global__ void k_rank(const unsigned long long* __restrict__ keys,
                       int* __restrict__ sel) {
  __shared__ unsigned long long lk[2048];
  int v = blockIdx.x * blockDim.x + threadIdx.x;
  unsigned long long kv = (v < N_NODES) ? keys[v] : 0xFFFFFFFFFFFFFFFFull;
  int cnt = 0;
  for (int base = 0; base < N_NODES; base += 2048) {
    int len = min(2048, N_NODES - base);
    for (int t = threadIdx.x; t < len; t += blockDim.x) lk[t] = keys[base + t];
    __syncthreads();
    for (int t = 0; t < len; ++t) cnt += (lk[t] < kv) ? 1 : 0;
    __syncthreads();
  }
  if (v < N_NODES) sel[v] = (cnt < BATCH) ? 1 : 0;
}

// Row histogram over source node i (LDS-local, merged with global atomics)
__global__ void k_hist(const int* __restrict__ e_i, int* __restrict__ cnt) {
  __shared__ int h[N_NODES];
  for (int t = threadIdx.x; t < N_NODES; t += blockDim.x) h[t] = 0;
  __syncthreads();
  int stride = gridDim.x * blockDim.x;
  for (int e = blockIdx.x * blockDim.x + threadIdx.x; e < N_EDGES; e += stride)
    atomicAdd(&h[e_i[e]], 1);
  __syncthreads();
  for (int t = threadIdx.x; t < N_NODES; t += blockDim.x) {
    int c = h[t];
    if (c) atomicAdd(&cnt[t], c);
  }
}

// One block, 1024 threads. Phase 1: exclusive scan of sel -> batch_nodes
// (compaction, replaces the serial single-wave k_compact). Phase 2: exclusive
// scan of cnt -> off, and fill[i] = off[i] (so scatter's atomicAdd returns the
// final slot directly).
__global__ void k_scan_all(const int* __restrict__ sel, int* __restrict__ bn,
                           float* __restrict__ outbn, const int* __restrict__ cnt,
                           int* __restrict__ off, int* __restrict__ fill) {
  __shared__ int ls[1024];
  const int PER = 10;  // 1024*10 >= 10000
  int tid = threadIdx.x;
  int base = tid * PER;

  // ---- Phase 1: sel -> bn / outbn ----
  {
    int s = 0;
    for (int k = 0; k < PER; ++k) {
      int i = base + k;
      if (i < N_NODES) s += sel[i];
    }
    ls[tid] = s;
    __syncthreads();
    for (int d = 1; d < 1024; d <<= 1) {
      int val = (tid >= d) ? ls[tid - d] : 0;
      __syncthreads();
      ls[tid] += val;
      __syncthreads();
    }
    int run = (tid > 0) ? ls[tid - 1] : 0;
    for (int k = 0; k < PER; ++k) {
      int i = base + k;
      if (i < N_NODES && sel[i]) {
        bn[run] = i;
        outbn[run] = (float)i;
        ++run;
      }
    }
  }
  __syncthreads();

  // ---- Phase 2: cnt -> off, fill ----
  {
    int s = 0;
    for (int k = 0; k < PER; ++k) {
      int i = base + k;
      if (i < N_NODES) s += cnt[i];
    }
    ls[tid] = s;
    __syncthreads();
    for (int d = 1; d < 1024; d <<= 1) {
      int val = (tid >= d) ? ls[tid - d] : 0;
      __syncthreads();
      ls[tid] += val;
      __syncthreads();
    }
    int run = (tid > 0) ? ls[tid - 1] : 0;
    for (int k = 0; k < PER; ++k) {
      int i = base + k;
      if (i < N_NODES) {
        off[i] = run;
        fill[i] = run;
        run += cnt[i];
      }
    }
    if (tid == 0) off[N_NODES] = N_EDGES;
  }
}

// batch_pairs via inverse triangular index. S(ii) = ii*(B-1) - ii*(ii-1)/2
__global__ void k_pairs(const int* __restrict__ bn, float* __restrict__ out) {
  int p = blockIdx.x * blockDim.x + threadIdx.x;
  if (p >= N_PAIRS) return;
  double t = 2.0 * BATCH - 1.0;
  int ii = (int)((t - sqrt(t * t - 8.0 * (double)p)) * 0.5);
  if (ii < 0) ii = 0;
  if (ii > BATCH - 2) ii = BATCH - 2;
  while (ii > 0 &&
         (long long)ii * (BATCH - 1) - (long long)ii * (ii - 1) / 2 > p) --ii;
  while ((long long)(ii + 1) * (BATCH - 1) - (long long)(ii + 1) * ii / 2 <= p) ++ii;
  long long S = (long long)ii * (BATCH - 1) - (long long)ii * (ii - 1) / 2;
  int jj = ii + 1 + (int)(p - S);
  out[p] = (float)bn[ii];
  out[N_PAIRS + p] = (float)bn[jj];
}

// Scatter edge indices (4B) into row buckets. fill[] pre-seeded with off[],
// so the atomicAdd return IS the slot. 4 independent atomic chains per thread
// for memory-level parallelism; int4-coalesced e_i read; e_j not touched.
__global__ void k_scatter(const int4* __restrict__ e_i4, int* __restrict__ fill,
                          unsigned* __restrict__ sk) {
  int t = blockIdx.x * blockDim.x + threadIdx.x;
  if (t >= N_EDGES / 4) return;
  int4 r = e_i4[t];
  unsigned e = 4u * (unsigned)t;
  int c0 = atomicAdd(&fill[r.x], 1);
  int c1 = atomicAdd(&fill[r.y], 1);
  int c2 = atomicAdd(&fill[r.z], 1);
  int c3 = atomicAdd(&fill[r.w], 1);
  sk[c0] = e;
  sk[c1] = e + 1;
  sk[c2] = e + 2;
  sk[c3] = e + 3;
}

// Per-row bitonic sort on key64=(j<<32)|idx (unique -> stable order by (j,idx)),
// then emit edges_sorted / batch_edge_times / batch_states / mask directly.
__global__ void __launch_bounds__(256) k_rowsort(
    const unsigned* __restrict__ sk, const int* __restrict__ e_j_arr,
    const int* __restrict__ off, const float* __restrict__ times,
    const int* __restrict__ states, const int* __restrict__ sel,
    float* __restrict__ out) {
  __shared__ unsigned long long key[2048];
  int row = blockIdx.x;
  int o0 = off[row], o1 = off[row + 1];
  int len = o1 - o0;
  if (len <= 0) return;
  if (len > 2048) len = 2048;  // statistically impossible (>60 sigma)
  int M = 2;
  while (M < len) M <<= 1;
  for (int t = threadIdx.x; t < M; t += blockDim.x) {
    if (t < len) {
      unsigned e = sk[o0 + t];
      key[t] = ((unsigned long long)(unsigned)e_j_arr[e] << 32) | e;
    } else {
      key[t] = 0xFFFFFFFFFFFFFFFFull;
    }
  }
  __syncthreads();
  for (int k = 2; k <= M; k <<= 1) {
    for (int j = k >> 1; j > 0; j >>= 1) {
      for (int t = threadIdx.x; t < M; t += blockDim.x) {
        int ixj = t ^ j;
        if (ixj > t) {
          unsigned long long a = key[t], b = key[ixj];
          bool up = ((t & k) == 0);
          if (up ? (a > b) : (a < b)) {
            key[t] = b;
            key[ixj] = a;
          }
        }
      }
      __syncthreads();
    }
  }
  int mi = sel[row];
  float frow = (float)row;
  for (int t = threadIdx.x; t < len; t += blockDim.x) {
    unsigned long long k = key[t];
    int j = (int)(k >> 32);
    int idx = (int)(k & 0xFFFFFFFFull);
    int p = o0 + t;
    out[OUT_ES0 + p] = frow;
    out[OUT_ES1 + p] = (float)j;
    bool m = (mi != 0) && (sel[j] != 0);
    float tm = times[idx];
    int st = states[idx];
    out[OUT_T + p] = m ? tm : 0.0f;
    out[OUT_S + p] = m ? (float)st : 0.0f;
    out[OUT_M + p] = m ? 1.0f : 0.0f;
  }
}

extern "C" void kernel_launch(void* const* d_in, const int* in_sizes, int n_in,
                              void* d_out, int out_size, void* d_ws, size_t ws_size,
                              hipStream_t stream) {
  const int* edges = (const int*)d_in[0];       // (2, E): [0..E)=i, [E..2E)=j
  const float* times = (const float*)d_in[1];
  const int* states = (const int*)d_in[2];
  const int* e_i = edges;
  const int* e_j = edges + N_EDGES;
  float* out = (float*)d_out;
  char* ws = (char*)d_ws;

  unsigned long long* keys = (unsigned long long*)(ws + WS_KEYS);
  int* sel = (int*)(ws + WS_SEL);
  int* bn = (int*)(ws + WS_BN);
  int* cnt = (int*)(ws + WS_CNT);
  int* fill = (int*)(ws + WS_FILL);
  int* off = (int*)(ws + WS_OFF);
  unsigned* sk = (unsigned*)(ws + WS_SCRATCH);

  hipMemsetAsync(ws + WS_CNT, 0, 40000, stream);  // cnt only

  k_scores<<<(N_NODES + 255) / 256, 256, 0, stream>>>(keys);
  k_rank<<<(N_NODES + 255) / 256, 256, 0, stream>>>(keys, sel);
  k_hist<<<128, 256, 0, stream>>>(e_i, cnt);
  k_scan_all<<<1, 1024, 0, stream>>>(sel, bn, out + OUT_BN, cnt, off, fill);
  k_pairs<<<(N_PAIRS + 255) / 256, 256, 0, stream>>>(bn, out + OUT_PAIRS0);
  k_scatter<<<(N_EDGES / 4 + 255) / 256, 256, 0, stream>>>((const int4*)e_i,
                                                           fill, sk);
  k_rowsort<<<N_NODES, 256, 0, stream>>>(sk, e_j, off, times, states, sel, out);
}

// Round 5
// 812.955 us; speedup vs baseline: 1.1864x; 1.1864x over previous
//
#include <hip/hip_runtime.h>
#include <stdint.h>
#include <math.h>

#define N_NODES  10000
#define N_EDGES  5000000
#define BATCH    2000
#define N_PAIRS  1999000   // BATCH*(BATCH-1)/2

// Output offsets (float32 elements), concatenated in reference return order
#define OUT_BN      0
#define OUT_PAIRS0  2000
#define OUT_PAIRS1  2001000
#define OUT_ES0     4000000
#define OUT_ES1     9000000
#define OUT_T       14000000
#define OUT_S       19000000
#define OUT_M       24000000

// Workspace layout (bytes)
#define WS_KEYS     0          // 10000 x u64
#define WS_SEL      80000      // 10000 x i32
#define WS_BN       120000     // 2000  x i32
#define WS_CNT      128000     // 10000 x i32   (zeroed by memset)
#define WS_FILL     168000     // 10000 x i32   (init to off[] by k_scan_all)
#define WS_OFF      208000     // 10001 x i32
#define WS_SCRATCH  248064     // fast: 5M x u64 keys; fallback: 5M x u32 idx

// key = (j << 24) | (idx << 1) | state   (14 + 23 + 1 = 38 bits)
// sort by key == sort by (j, idx) since idx is unique.

// ---------------------------------------------------------------------------
// Gumbel score -> descending-sortable key with ascending-index tiebreak.
__device__ __forceinline__ unsigned long long score_key(int w, unsigned bits) {
  const float TINY = 1.17549435e-38f;
  float uf = __uint_as_float((bits >> 9) | 0x3f800000u) - 1.0f;
  float val = fmaxf(TINY, uf + TINY);
  float t1 = (float)log((double)val);            // inner log, rounded to f32
  float gmb = -(float)log((double)(-t1));        // outer log on f32-rounded input
  float score = (w > 0) ? ((float)log((double)w) + gmb) : (-INFINITY);
  unsigned fb = __float_as_uint(score);
  unsigned s = (fb & 0x80000000u) ? ~fb : (fb | 0x80000000u);
  unsigned d = ~s;
  return ((unsigned long long)d << 32) | (unsigned)w;
}

// JAX threefry2x32, partitionable mode: (x0,x1)=(0,i)+key; bits = out0^out1.
__global__ void k_scores(unsigned long long* __restrict__ keys) {
  int v = blockIdx.x * blockDim.x + threadIdx.x;
  if (v >= N_NODES) return;
  unsigned ks[3] = {0u, 19u, 0u ^ 19u ^ 0x1BD11BDAu};
  unsigned x0 = 0u + ks[0];
  unsigned x1 = (unsigned)v + ks[1];
  const int R0[4] = {13, 15, 26, 6};
  const int R1[4] = {17, 29, 16, 24};
#pragma unroll
  for (int g = 0; g < 5; ++g) {
    const int* R = (g & 1) ? R1 : R0;
#pragma unroll
    for (int r = 0; r < 4; ++r) {
      x0 += x1;
      x1 = (x1 << R[r]) | (x1 >> (32 - R[r]));
      x1 ^= x0;
    }
    x0 += ks[(g + 1) % 3];
    x1 += ks[(g + 2) % 3] + (unsigned)(g + 1);
  }
  keys[v] = score_key(v, x0 ^ x1);
}

// Rank each node's key among all 10000 (unique keys); selected iff rank < 2000.
__global__ void k_rank(const unsigned long long* __restrict__ keys,
                       int* __restrict__ sel) {
  __shared__ unsigned long long lk[2048];
  int v = blockIdx.x * blockDim.x + threadIdx.x;
  unsigned long long kv = (v < N_NODES) ? keys[v] : 0xFFFFFFFFFFFFFFFFull;
  int cnt = 0;
  for (int base = 0; base < N_NODES; base += 2048) {
    int len = min(2048, N_NODES - base);
    for (int t = threadIdx.x; t < len; t += blockDim.x) lk[t] = keys[base + t];
    __syncthreads();
    for (int t = 0; t < len; ++t) cnt += (lk[t] < kv) ? 1 : 0;
    __syncthreads();
  }
  if (v < N_NODES) sel[v] = (cnt < BATCH) ? 1 : 0;
}

// Row histogram over source node i (LDS-local, merged with global atomics)
__global__ void k_hist(const int4* __restrict__ e_i4, int* __restrict__ cnt) {
  __shared__ int h[N_NODES];
  for (int t = threadIdx.x; t < N_NODES; t += blockDim.x) h[t] = 0;
  __syncthreads();
  int stride = gridDim.x * blockDim.x;
  for (int t = blockIdx.x * blockDim.x + threadIdx.x; t < N_EDGES / 4; t += stride) {
    int4 r = e_i4[t];
    atomicAdd(&h[r.x], 1);
    atomicAdd(&h[r.y], 1);
    atomicAdd(&h[r.z], 1);
    atomicAdd(&h[r.w], 1);
  }
  __syncthreads();
  for (int t = threadIdx.x; t < N_NODES; t += blockDim.x) {
    int c = h[t];
    if (c) atomicAdd(&cnt[t], c);
  }
}

// One block, 1024 threads. Phase 1: compaction scan sel -> batch_nodes.
// Phase 2: exclusive scan cnt -> off, and fill[i] = off[i].
__global__ void k_scan_all(const int* __restrict__ sel, int* __restrict__ bn,
                           float* __restrict__ outbn, const int* __restrict__ cnt,
                           int* __restrict__ off, int* __restrict__ fill) {
  __shared__ int ls[1024];
  const int PER = 10;  // 1024*10 >= 10000
  int tid = threadIdx.x;
  int base = tid * PER;
  {
    int s = 0;
    for (int k = 0; k < PER; ++k) {
      int i = base + k;
      if (i < N_NODES) s += sel[i];
    }
    ls[tid] = s;
    __syncthreads();
    for (int d = 1; d < 1024; d <<= 1) {
      int val = (tid >= d) ? ls[tid - d] : 0;
      __syncthreads();
      ls[tid] += val;
      __syncthreads();
    }
    int run = (tid > 0) ? ls[tid - 1] : 0;
    for (int k = 0; k < PER; ++k) {
      int i = base + k;
      if (i < N_NODES && sel[i]) {
        bn[run] = i;
        outbn[run] = (float)i;
        ++run;
      }
    }
  }
  __syncthreads();
  {
    int s = 0;
    for (int k = 0; k < PER; ++k) {
      int i = base + k;
      if (i < N_NODES) s += cnt[i];
    }
    ls[tid] = s;
    __syncthreads();
    for (int d = 1; d < 1024; d <<= 1) {
      int val = (tid >= d) ? ls[tid - d] : 0;
      __syncthreads();
      ls[tid] += val;
      __syncthreads();
    }
    int run = (tid > 0) ? ls[tid - 1] : 0;
    for (int k = 0; k < PER; ++k) {
      int i = base + k;
      if (i < N_NODES) {
        off[i] = run;
        fill[i] = run;
        run += cnt[i];
      }
    }
    if (tid == 0) off[N_NODES] = N_EDGES;
  }
}

// batch_pairs via inverse triangular index. S(ii) = ii*(B-1) - ii*(ii-1)/2
__global__ void k_pairs(const int* __restrict__ bn, float* __restrict__ out) {
  int p = blockIdx.x * blockDim.x + threadIdx.x;
  if (p >= N_PAIRS) return;
  double t = 2.0 * BATCH - 1.0;
  int ii = (int)((t - sqrt(t * t - 8.0 * (double)p)) * 0.5);
  if (ii < 0) ii = 0;
  if (ii > BATCH - 2) ii = BATCH - 2;
  while (ii > 0 &&
         (long long)ii * (BATCH - 1) - (long long)ii * (ii - 1) / 2 > p) --ii;
  while ((long long)(ii + 1) * (BATCH - 1) - (long long)(ii + 1) * ii / 2 <= p) ++ii;
  long long S = (long long)ii * (BATCH - 1) - (long long)ii * (ii - 1) / 2;
  int jj = ii + 1 + (int)(p - S);
  out[p] = (float)bn[ii];
  out[N_PAIRS + p] = (float)bn[jj];
}

// FAST scatter: 8 edges/thread, coalesced int4 reads of e_i/e_j/states,
// 8 independent atomic chains, write full sort key u64 to bucket slot.
__global__ void __launch_bounds__(256) k_scatter_key(
    const int4* __restrict__ e_i4, const int4* __restrict__ e_j4,
    const int4* __restrict__ st4, int* __restrict__ fill,
    unsigned long long* __restrict__ sk) {
  int t = blockIdx.x * blockDim.x + threadIdx.x;
  if (t >= N_EDGES / 8) return;
  int4 a0 = e_i4[2 * t], a1 = e_i4[2 * t + 1];
  int4 j0 = e_j4[2 * t], j1 = e_j4[2 * t + 1];
  int4 s0 = st4[2 * t], s1 = st4[2 * t + 1];
  unsigned e = 8u * (unsigned)t;
  int c0 = atomicAdd(&fill[a0.x], 1);
  int c1 = atomicAdd(&fill[a0.y], 1);
  int c2 = atomicAdd(&fill[a0.z], 1);
  int c3 = atomicAdd(&fill[a0.w], 1);
  int c4 = atomicAdd(&fill[a1.x], 1);
  int c5 = atomicAdd(&fill[a1.y], 1);
  int c6 = atomicAdd(&fill[a1.z], 1);
  int c7 = atomicAdd(&fill[a1.w], 1);
#define MK(jv, ev, sv) ((((unsigned long long)(unsigned)(jv)) << 24) | \
                        (((unsigned long long)(unsigned)(ev)) << 1) | \
                        (unsigned long long)(unsigned)(sv))
  sk[c0] = MK(j0.x, e + 0, s0.x);
  sk[c1] = MK(j0.y, e + 1, s0.y);
  sk[c2] = MK(j0.z, e + 2, s0.z);
  sk[c3] = MK(j0.w, e + 3, s0.w);
  sk[c4] = MK(j1.x, e + 4, s1.x);
  sk[c5] = MK(j1.y, e + 5, s1.y);
  sk[c6] = MK(j1.z, e + 6, s1.z);
  sk[c7] = MK(j1.w, e + 7, s1.w);
#undef MK
}

// FALLBACK scatter (ws too small for u64 keys): 4B idx only.
__global__ void __launch_bounds__(256) k_scatter_idx(
    const int4* __restrict__ e_i4, int* __restrict__ fill,
    unsigned* __restrict__ sk) {
  int t = blockIdx.x * blockDim.x + threadIdx.x;
  if (t >= N_EDGES / 4) return;
  int4 r = e_i4[t];
  unsigned e = 4u * (unsigned)t;
  int c0 = atomicAdd(&fill[r.x], 1);
  int c1 = atomicAdd(&fill[r.y], 1);
  int c2 = atomicAdd(&fill[r.z], 1);
  int c3 = atomicAdd(&fill[r.w], 1);
  sk[c0] = e;
  sk[c1] = e + 1;
  sk[c2] = e + 2;
  sk[c3] = e + 3;
}

// FAST rowsort: keys already carry (j, idx, state). Only gather = times[idx],
// and ONLY for masked entries (sel[i] && sel[j], ~4% of edges).
__global__ void __launch_bounds__(256) k_rowsort_key(
    const unsigned long long* __restrict__ sk, const int* __restrict__ off,
    const float* __restrict__ times, const int* __restrict__ sel,
    float* __restrict__ out) {
  __shared__ unsigned long long key[2048];
  int row = blockIdx.x;
  int o0 = off[row], o1 = off[row + 1];
  int len = o1 - o0;
  if (len <= 0) return;
  if (len > 2048) len = 2048;  // statistically impossible (>60 sigma)
  int M = 2;
  while (M < len) M <<= 1;
  for (int t = threadIdx.x; t < M; t += blockDim.x)
    key[t] = (t < len) ? sk[o0 + t] : 0xFFFFFFFFFFFFFFFFull;
  __syncthreads();
  for (int k = 2; k <= M; k <<= 1) {
    for (int j = k >> 1; j > 0; j >>= 1) {
      for (int t = threadIdx.x; t < M; t += blockDim.x) {
        int ixj = t ^ j;
        if (ixj > t) {
          unsigned long long a = key[t], b = key[ixj];
          bool up = ((t & k) == 0);
          if (up ? (a > b) : (a < b)) {
            key[t] = b;
            key[ixj] = a;
          }
        }
      }
      __syncthreads();
    }
  }
  int mi = sel[row];
  float frow = (float)row;
  for (int t = threadIdx.x; t < len; t += blockDim.x) {
    unsigned long long k = key[t];
    int j = (int)(k >> 24);
    int idx = (int)((k >> 1) & 0x7FFFFFull);
    int st = (int)(k & 1ull);
    int p = o0 + t;
    out[OUT_ES0 + p] = frow;
    out[OUT_ES1 + p] = (float)j;
    bool m = (mi != 0) && (sel[j] != 0);
    float tm = 0.0f;
    if (m) tm = times[idx];                 // exec-masked gather, ~4% of edges
    out[OUT_T + p] = tm;
    out[OUT_S + p] = m ? (float)st : 0.0f;
    out[OUT_M + p] = m ? 1.0f : 0.0f;
  }
}

// FALLBACK rowsort: build keys via e_j gather; times/states gathered masked.
__global__ void __launch_bounds__(256) k_rowsort_idx(
    const unsigned* __restrict__ sk, const int* __restrict__ e_j_arr,
    const int* __restrict__ off, const float* __restrict__ times,
    const int* __restrict__ states, const int* __restrict__ sel,
    float* __restrict__ out) {
  __shared__ unsigned long long key[2048];
  int row = blockIdx.x;
  int o0 = off[row], o1 = off[row + 1];
  int len = o1 - o0;
  if (len <= 0) return;
  if (len > 2048) len = 2048;
  int M = 2;
  while (M < len) M <<= 1;
  for (int t = threadIdx.x; t < M; t += blockDim.x) {
    if (t < len) {
      unsigned e = sk[o0 + t];
      key[t] = ((unsigned long long)(unsigned)e_j_arr[e] << 32) | e;
    } else {
      key[t] = 0xFFFFFFFFFFFFFFFFull;
    }
  }
  __syncthreads();
  for (int k = 2; k <= M; k <<= 1) {
    for (int j = k >> 1; j > 0; j >>= 1) {
      for (int t = threadIdx.x; t < M; t += blockDim.x) {
        int ixj = t ^ j;
        if (ixj > t) {
          unsigned long long a = key[t], b = key[ixj];
          bool up = ((t & k) == 0);
          if (up ? (a > b) : (a < b)) {
            key[t] = b;
            key[ixj] = a;
          }
        }
      }
      __syncthreads();
    }
  }
  int mi = sel[row];
  float frow = (float)row;
  for (int t = threadIdx.x; t < len; t += blockDim.x) {
    unsigned long long k = key[t];
    int j = (int)(k >> 32);
    int idx = (int)(k & 0xFFFFFFFFull);
    int p = o0 + t;
    out[OUT_ES0 + p] = frow;
    out[OUT_ES1 + p] = (float)j;
    bool m = (mi != 0) && (sel[j] != 0);
    float tm = 0.0f, sv = 0.0f;
    if (m) {
      tm = times[idx];
      sv = (float)states[idx];
    }
    out[OUT_T + p] = tm;
    out[OUT_S + p] = sv;
    out[OUT_M + p] = m ? 1.0f : 0.0f;
  }
}

extern "C" void kernel_launch(void* const* d_in, const int* in_sizes, int n_in,
                              void* d_out, int out_size, void* d_ws, size_t ws_size,
                              hipStream_t stream) {
  const int* edges = (const int*)d_in[0];       // (2, E): [0..E)=i, [E..2E)=j
  const float* times = (const float*)d_in[1];
  const int* states = (const int*)d_in[2];
  const int* e_i = edges;
  const int* e_j = edges + N_EDGES;
  float* out = (float*)d_out;
  char* ws = (char*)d_ws;

  unsigned long long* keys = (unsigned long long*)(ws + WS_KEYS);
  int* sel = (int*)(ws + WS_SEL);
  int* bn = (int*)(ws + WS_BN);
  int* cnt = (int*)(ws + WS_CNT);
  int* fill = (int*)(ws + WS_FILL);
  int* off = (int*)(ws + WS_OFF);
  unsigned long long* sk64 = (unsigned long long*)(ws + WS_SCRATCH);
  unsigned* sk32 = (unsigned*)(ws + WS_SCRATCH);
  int use64 = (ws_size >= (size_t)WS_SCRATCH + 8ull * N_EDGES) ? 1 : 0;

  hipMemsetAsync(ws + WS_CNT, 0, 40000, stream);  // cnt only

  k_scores<<<(N_NODES + 255) / 256, 256, 0, stream>>>(keys);
  k_rank<<<(N_NODES + 255) / 256, 256, 0, stream>>>(keys, sel);
  k_hist<<<128, 256, 0, stream>>>((const int4*)e_i, cnt);
  k_scan_all<<<1, 1024, 0, stream>>>(sel, bn, out + OUT_BN, cnt, off, fill);
  k_pairs<<<(N_PAIRS + 255) / 256, 256, 0, stream>>>(bn, out + OUT_PAIRS0);
  if (use64) {
    k_scatter_key<<<(N_EDGES / 8 + 255) / 256, 256, 0, stream>>>(
        (const int4*)e_i, (const int4*)e_j, (const int4*)states, fill, sk64);
    k_rowsort_key<<<N_NODES, 256, 0, stream>>>(sk64, off, times, sel, out);
  } else {
    k_scatter_idx<<<(N_EDGES / 4 + 255) / 256, 256, 0, stream>>>(
        (const int4*)e_i, fill, sk32);
    k_rowsort_idx<<<N_NODES, 256, 0, stream>>>(sk32, e_j, off, times, states,
                                               sel, out);
  }
}

// Round 6
// 630.756 us; speedup vs baseline: 1.5291x; 1.2889x over previous
//
#include <hip/hip_runtime.h>
#include <stdint.h>
#include <math.h>

#define N_NODES  10000
#define N_EDGES  5000000
#define BATCH    2000
#define N_PAIRS  1999000   // BATCH*(BATCH-1)/2

// Output offsets (float32 elements), concatenated in reference return order
#define OUT_BN      0
#define OUT_PAIRS0  2000
#define OUT_PAIRS1  2001000
#define OUT_ES0     4000000
#define OUT_ES1     9000000
#define OUT_T       14000000
#define OUT_S       19000000
#define OUT_M       24000000

// Workspace layout (bytes) — identical to R5 (ws >= 40.25 MB proven)
#define WS_KEYS     0          // 10000 x u64 (dead after k_rank; fill1 aliases here)
#define WS_SEL      80000      // 10000 x i32
#define WS_BN       120000     // 2000  x i32
#define WS_CNT      128000     // 10000 x i32   (zeroed by memset)
#define WS_FILL     168000     // 10000 x i32   (init to off[] by k_scan_all)
#define WS_OFF      208000     // 10001 x i32
#define WS_SCRATCH  248064     // fast: 5M x u64 keys; fallback: 5M x u32 idx

// Sort key: (i<<38) | (j<<24) | (idx<<1) | state  (14+14+23+1 = 52 bits).
// Within a row i is constant, idx unique -> order == stable (j, idx).

#define RPB_LOG  7
#define NB1      79            // ceil(10000 / 128) coarse buckets
#define CHUNK    8192          // edges per partition block (256 thr x 32)

// ---------------------------------------------------------------------------
__device__ __forceinline__ unsigned long long score_key(int w, unsigned bits) {
  const float TINY = 1.17549435e-38f;
  float uf = __uint_as_float((bits >> 9) | 0x3f800000u) - 1.0f;
  float val = fmaxf(TINY, uf + TINY);
  float t1 = (float)log((double)val);            // inner log, rounded to f32
  float gmb = -(float)log((double)(-t1));        // outer log on f32-rounded input
  float score = (w > 0) ? ((float)log((double)w) + gmb) : (-INFINITY);
  unsigned fb = __float_as_uint(score);
  unsigned s = (fb & 0x80000000u) ? ~fb : (fb | 0x80000000u);
  unsigned d = ~s;
  return ((unsigned long long)d << 32) | (unsigned)w;
}

// JAX threefry2x32, partitionable mode: (x0,x1)=(0,i)+key; bits = out0^out1.
__global__ void k_scores(unsigned long long* __restrict__ keys) {
  int v = blockIdx.x * blockDim.x + threadIdx.x;
  if (v >= N_NODES) return;
  unsigned ks[3] = {0u, 19u, 0u ^ 19u ^ 0x1BD11BDAu};
  unsigned x0 = 0u + ks[0];
  unsigned x1 = (unsigned)v + ks[1];
  const int R0[4] = {13, 15, 26, 6};
  const int R1[4] = {17, 29, 16, 24};
#pragma unroll
  for (int g = 0; g < 5; ++g) {
    const int* R = (g & 1) ? R1 : R0;
#pragma unroll
    for (int r = 0; r < 4; ++r) {
      x0 += x1;
      x1 = (x1 << R[r]) | (x1 >> (32 - R[r]));
      x1 ^= x0;
    }
    x0 += ks[(g + 1) % 3];
    x1 += ks[(g + 2) % 3] + (unsigned)(g + 1);
  }
  keys[v] = score_key(v, x0 ^ x1);
}

// Rank each node's key among all 10000 (unique keys); selected iff rank < 2000.
__global__ void k_rank(const unsigned long long* __restrict__ keys,
                       int* __restrict__ sel) {
  __shared__ unsigned long long lk[2048];
  int v = blockIdx.x * blockDim.x + threadIdx.x;
  unsigned long long kv = (v < N_NODES) ? keys[v] : 0xFFFFFFFFFFFFFFFFull;
  int cnt = 0;
  for (int base = 0; base < N_NODES; base += 2048) {
    int len = min(2048, N_NODES - base);
    for (int t = threadIdx.x; t < len; t += blockDim.x) lk[t] = keys[base + t];
    __syncthreads();
    for (int t = 0; t < len; ++t) cnt += (lk[t] < kv) ? 1 : 0;
    __syncthreads();
  }
  if (v < N_NODES) sel[v] = (cnt < BATCH) ? 1 : 0;
}

// Row histogram over source node i (LDS-local, merged with global atomics)
__global__ void k_hist(const int4* __restrict__ e_i4, int* __restrict__ cnt) {
  __shared__ int h[N_NODES];
  for (int t = threadIdx.x; t < N_NODES; t += blockDim.x) h[t] = 0;
  __syncthreads();
  int stride = gridDim.x * blockDim.x;
  for (int t = blockIdx.x * blockDim.x + threadIdx.x; t < N_EDGES / 4; t += stride) {
    int4 r = e_i4[t];
    atomicAdd(&h[r.x], 1);
    atomicAdd(&h[r.y], 1);
    atomicAdd(&h[r.z], 1);
    atomicAdd(&h[r.w], 1);
  }
  __syncthreads();
  for (int t = threadIdx.x; t < N_NODES; t += blockDim.x) {
    int c = h[t];
    if (c) atomicAdd(&cnt[t], c);
  }
}

// One block, 1024 threads. Phase 1: compaction scan sel -> batch_nodes.
// Phase 2: exclusive scan cnt -> off; fill[i] = off[i]; seed coarse-bucket
// cursors fill1[b] = off[b*128].
__global__ void k_scan_all(const int* __restrict__ sel, int* __restrict__ bn,
                           float* __restrict__ outbn, const int* __restrict__ cnt,
                           int* __restrict__ off, int* __restrict__ fill,
                           int* __restrict__ fill1) {
  __shared__ int ls[1024];
  const int PER = 10;  // 1024*10 >= 10000
  int tid = threadIdx.x;
  int base = tid * PER;
  {
    int s = 0;
    for (int k = 0; k < PER; ++k) {
      int i = base + k;
      if (i < N_NODES) s += sel[i];
    }
    ls[tid] = s;
    __syncthreads();
    for (int d = 1; d < 1024; d <<= 1) {
      int val = (tid >= d) ? ls[tid - d] : 0;
      __syncthreads();
      ls[tid] += val;
      __syncthreads();
    }
    int run = (tid > 0) ? ls[tid - 1] : 0;
    for (int k = 0; k < PER; ++k) {
      int i = base + k;
      if (i < N_NODES && sel[i]) {
        bn[run] = i;
        outbn[run] = (float)i;
        ++run;
      }
    }
  }
  __syncthreads();
  {
    int s = 0;
    for (int k = 0; k < PER; ++k) {
      int i = base + k;
      if (i < N_NODES) s += cnt[i];
    }
    ls[tid] = s;
    __syncthreads();
    for (int d = 1; d < 1024; d <<= 1) {
      int val = (tid >= d) ? ls[tid - d] : 0;
      __syncthreads();
      ls[tid] += val;
      __syncthreads();
    }
    int run = (tid > 0) ? ls[tid - 1] : 0;
    for (int k = 0; k < PER; ++k) {
      int i = base + k;
      if (i < N_NODES) {
        off[i] = run;
        fill[i] = run;
        if ((i & ((1 << RPB_LOG) - 1)) == 0) fill1[i >> RPB_LOG] = run;
        run += cnt[i];
      }
    }
    if (tid == 0) off[N_NODES] = N_EDGES;
  }
}

// batch_pairs via inverse triangular index. S(ii) = ii*(B-1) - ii*(ii-1)/2
__global__ void k_pairs(const int* __restrict__ bn, float* __restrict__ out) {
  int p = blockIdx.x * blockDim.x + threadIdx.x;
  if (p >= N_PAIRS) return;
  double t = 2.0 * BATCH - 1.0;
  int ii = (int)((t - sqrt(t * t - 8.0 * (double)p)) * 0.5);
  if (ii < 0) ii = 0;
  if (ii > BATCH - 2) ii = BATCH - 2;
  while (ii > 0 &&
         (long long)ii * (BATCH - 1) - (long long)ii * (ii - 1) / 2 > p) --ii;
  while ((long long)(ii + 1) * (BATCH - 1) - (long long)(ii + 1) * ii / 2 <= p) ++ii;
  long long S = (long long)ii * (BATCH - 1) - (long long)ii * (ii - 1) / 2;
  int jj = ii + 1 + (int)(p - S);
  out[p] = (float)bn[ii];
  out[N_PAIRS + p] = (float)bn[jj];
}

// P1: coarse partition into 79 buckets (rows i>>7). Block-local ranks =>
// each block writes ~830B contiguous runs per bucket => full-line evictions.
__global__ void __launch_bounds__(256) k_part1(
    const int* __restrict__ e_i, const int* __restrict__ e_j,
    const int* __restrict__ st, int* __restrict__ fill1,
    unsigned long long* __restrict__ stage) {
  __shared__ int h[NB1], basec[NB1], c2[NB1];
  int c0 = blockIdx.x * CHUNK;
  for (int t = threadIdx.x; t < NB1; t += 256) { h[t] = 0; c2[t] = 0; }
  __syncthreads();
  int iv[CHUNK / 256];
#pragma unroll
  for (int k = 0; k < CHUNK / 256; ++k) {
    int e = c0 + threadIdx.x + 256 * k;
    if (e < N_EDGES) {
      int i = e_i[e];
      iv[k] = i;
      atomicAdd(&h[i >> RPB_LOG], 1);
    } else {
      iv[k] = -1;
    }
  }
  __syncthreads();
  for (int t = threadIdx.x; t < NB1; t += 256)
    basec[t] = h[t] ? atomicAdd(&fill1[t], h[t]) : 0;
  __syncthreads();
#pragma unroll
  for (int k = 0; k < CHUNK / 256; ++k) {
    int e = c0 + threadIdx.x + 256 * k;
    if (e >= N_EDGES) break;
    int i = iv[k];
    int b = i >> RPB_LOG;
    int j = e_j[e];
    int s = st[e];
    int r = atomicAdd(&c2[b], 1);
    unsigned long long key = ((unsigned long long)(unsigned)i << 38) |
                             ((unsigned long long)(unsigned)j << 24) |
                             ((unsigned long long)(unsigned)e << 1) |
                             (unsigned long long)(unsigned)s;
    stage[basec[b] + r] = key;
  }
}

// P2: fine partition bucket-grouped keys into exact row slots. A contiguous
// CHUNK spans <=2 coarse buckets => rows in [rowbase, rowbase+255].
__global__ void __launch_bounds__(256) k_part2(
    const unsigned long long* __restrict__ stage, int* __restrict__ fill,
    unsigned long long* __restrict__ sk) {
  __shared__ int h[256], baser[256], c2[256];
  __shared__ int rowbase_s;
  int c0 = blockIdx.x * CHUNK;
  for (int t = threadIdx.x; t < 256; t += 256) { h[t] = 0; c2[t] = 0; }
  if (threadIdx.x == 0) {
    int i0 = (int)(stage[c0] >> 38);
    rowbase_s = (i0 >> RPB_LOG) << RPB_LOG;
  }
  __syncthreads();
  int rowbase = rowbase_s;
#pragma unroll
  for (int k = 0; k < CHUNK / 256; ++k) {
    int e = c0 + threadIdx.x + 256 * k;
    if (e < N_EDGES) {
      int lr = (int)(stage[e] >> 38) - rowbase;
      atomicAdd(&h[lr], 1);
    }
  }
  __syncthreads();
  {
    int t = threadIdx.x;
    baser[t] = h[t] ? atomicAdd(&fill[rowbase + t], h[t]) : 0;
  }
  __syncthreads();
#pragma unroll
  for (int k = 0; k < CHUNK / 256; ++k) {
    int e = c0 + threadIdx.x + 256 * k;
    if (e >= N_EDGES) break;
    unsigned long long kv = stage[e];
    int lr = (int)(kv >> 38) - rowbase;
    int r = atomicAdd(&c2[lr], 1);
    sk[baser[lr] + r] = kv;
  }
}

// Rowsort: keys carry (i, j, idx, state). Only gather = times[idx], masked
// (sel[i] && sel[j], ~4% of edges).
__global__ void __launch_bounds__(256) k_rowsort_key(
    const unsigned long long* __restrict__ sk, const int* __restrict__ off,
    const float* __restrict__ times, const int* __restrict__ sel,
    float* __restrict__ out) {
  __shared__ unsigned long long key[2048];
  int row = blockIdx.x;
  int o0 = off[row], o1 = off[row + 1];
  int len = o1 - o0;
  if (len <= 0) return;
  if (len > 2048) len = 2048;  // statistically impossible (>60 sigma)
  int M = 2;
  while (M < len) M <<= 1;
  for (int t = threadIdx.x; t < M; t += blockDim.x)
    key[t] = (t < len) ? sk[o0 + t] : 0xFFFFFFFFFFFFFFFFull;
  __syncthreads();
  for (int k = 2; k <= M; k <<= 1) {
    for (int j = k >> 1; j > 0; j >>= 1) {
      for (int t = threadIdx.x; t < M; t += blockDim.x) {
        int ixj = t ^ j;
        if (ixj > t) {
          unsigned long long a = key[t], b = key[ixj];
          bool up = ((t & k) == 0);
          if (up ? (a > b) : (a < b)) {
            key[t] = b;
            key[ixj] = a;
          }
        }
      }
      __syncthreads();
    }
  }
  int mi = sel[row];
  float frow = (float)row;
  for (int t = threadIdx.x; t < len; t += blockDim.x) {
    unsigned long long k = key[t];
    int j = (int)((k >> 24) & 0x3FFFull);
    int idx = (int)((k >> 1) & 0x7FFFFFull);
    int st = (int)(k & 1ull);
    int p = o0 + t;
    out[OUT_ES0 + p] = frow;
    out[OUT_ES1 + p] = (float)j;
    bool m = (mi != 0) && (sel[j] != 0);
    float tm = 0.0f;
    if (m) tm = times[idx];                 // exec-masked gather, ~4% of edges
    out[OUT_T + p] = tm;
    out[OUT_S + p] = m ? (float)st : 0.0f;
    out[OUT_M + p] = m ? 1.0f : 0.0f;
  }
}

// ---- Fallback path (ws too small for u64 keys): R4-style 4B idx scatter ----
__global__ void __launch_bounds__(256) k_scatter_idx(
    const int4* __restrict__ e_i4, int* __restrict__ fill,
    unsigned* __restrict__ sk) {
  int t = blockIdx.x * blockDim.x + threadIdx.x;
  if (t >= N_EDGES / 4) return;
  int4 r = e_i4[t];
  unsigned e = 4u * (unsigned)t;
  int c0 = atomicAdd(&fill[r.x], 1);
  int c1 = atomicAdd(&fill[r.y], 1);
  int c2 = atomicAdd(&fill[r.z], 1);
  int c3 = atomicAdd(&fill[r.w], 1);
  sk[c0] = e;
  sk[c1] = e + 1;
  sk[c2] = e + 2;
  sk[c3] = e + 3;
}

__global__ void __launch_bounds__(256) k_rowsort_idx(
    const unsigned* __restrict__ sk, const int* __restrict__ e_j_arr,
    const int* __restrict__ off, const float* __restrict__ times,
    const int* __restrict__ states, const int* __restrict__ sel,
    float* __restrict__ out) {
  __shared__ unsigned long long key[2048];
  int row = blockIdx.x;
  int o0 = off[row], o1 = off[row + 1];
  int len = o1 - o0;
  if (len <= 0) return;
  if (len > 2048) len = 2048;
  int M = 2;
  while (M < len) M <<= 1;
  for (int t = threadIdx.x; t < M; t += blockDim.x) {
    if (t < len) {
      unsigned e = sk[o0 + t];
      key[t] = ((unsigned long long)(unsigned)e_j_arr[e] << 32) | e;
    } else {
      key[t] = 0xFFFFFFFFFFFFFFFFull;
    }
  }
  __syncthreads();
  for (int k = 2; k <= M; k <<= 1) {
    for (int j = k >> 1; j > 0; j >>= 1) {
      for (int t = threadIdx.x; t < M; t += blockDim.x) {
        int ixj = t ^ j;
        if (ixj > t) {
          unsigned long long a = key[t], b = key[ixj];
          bool up = ((t & k) == 0);
          if (up ? (a > b) : (a < b)) {
            key[t] = b;
            key[ixj] = a;
          }
        }
      }
      __syncthreads();
    }
  }
  int mi = sel[row];
  float frow = (float)row;
  for (int t = threadIdx.x; t < len; t += blockDim.x) {
    unsigned long long k = key[t];
    int j = (int)(k >> 32);
    int idx = (int)(k & 0xFFFFFFFFull);
    int p = o0 + t;
    out[OUT_ES0 + p] = frow;
    out[OUT_ES1 + p] = (float)j;
    bool m = (mi != 0) && (sel[j] != 0);
    float tm = 0.0f, sv = 0.0f;
    if (m) {
      tm = times[idx];
      sv = (float)states[idx];
    }
    out[OUT_T + p] = tm;
    out[OUT_S + p] = sv;
    out[OUT_M + p] = m ? 1.0f : 0.0f;
  }
}

extern "C" void kernel_launch(void* const* d_in, const int* in_sizes, int n_in,
                              void* d_out, int out_size, void* d_ws, size_t ws_size,
                              hipStream_t stream) {
  const int* edges = (const int*)d_in[0];       // (2, E): [0..E)=i, [E..2E)=j
  const float* times = (const float*)d_in[1];
  const int* states = (const int*)d_in[2];
  const int* e_i = edges;
  const int* e_j = edges + N_EDGES;
  float* out = (float*)d_out;
  char* ws = (char*)d_ws;

  unsigned long long* keys = (unsigned long long*)(ws + WS_KEYS);
  int* fill1 = (int*)(ws + WS_KEYS);            // aliases keys (dead after k_rank)
  int* sel = (int*)(ws + WS_SEL);
  int* bn = (int*)(ws + WS_BN);
  int* cnt = (int*)(ws + WS_CNT);
  int* fill = (int*)(ws + WS_FILL);
  int* off = (int*)(ws + WS_OFF);
  unsigned long long* sk64 = (unsigned long long*)(ws + WS_SCRATCH);
  unsigned* sk32 = (unsigned*)(ws + WS_SCRATCH);
  // Staging buffer for P1 output: the es0/es1 output region (exactly 40 MB),
  // fully consumed by P2 before k_rowsort_key overwrites it.
  unsigned long long* stage = (unsigned long long*)(out + OUT_ES0);
  int use64 = (ws_size >= (size_t)WS_SCRATCH + 8ull * N_EDGES) ? 1 : 0;

  hipMemsetAsync(ws + WS_CNT, 0, 40000, stream);  // cnt only

  k_scores<<<(N_NODES + 255) / 256, 256, 0, stream>>>(keys);
  k_rank<<<(N_NODES + 255) / 256, 256, 0, stream>>>(keys, sel);
  k_hist<<<128, 256, 0, stream>>>((const int4*)e_i, cnt);
  k_scan_all<<<1, 1024, 0, stream>>>(sel, bn, out + OUT_BN, cnt, off, fill, fill1);
  k_pairs<<<(N_PAIRS + 255) / 256, 256, 0, stream>>>(bn, out + OUT_PAIRS0);
  if (use64) {
    int nblk = (N_EDGES + CHUNK - 1) / CHUNK;
    k_part1<<<nblk, 256, 0, stream>>>(e_i, e_j, states, fill1, stage);
    k_part2<<<nblk, 256, 0, stream>>>(stage, fill, sk64);
    k_rowsort_key<<<N_NODES, 256, 0, stream>>>(sk64, off, times, sel, out);
  } else {
    k_scatter_idx<<<(N_EDGES / 4 + 255) / 256, 256, 0, stream>>>(
        (const int4*)e_i, fill, sk32);
    k_rowsort_idx<<<N_NODES, 256, 0, stream>>>(sk32, e_j, off, times, states,
                                               sel, out);
  }
}